// Round 1
// 211.919 us; speedup vs baseline: 1.1875x; 1.1875x over previous
//
#include <hip/hip_runtime.h>

#define BB 8
#define TT 1024
#define FF 512
#define DD 64
#define LCH 16
#define CCH (TT / LCH)
#define PR 8   // token rows per lnproj block

__device__ __forceinline__ float wave_sum64(float v) {
  #pragma unroll
  for (int m = 32; m >= 1; m >>= 1) v += __shfl_xor(v, m, 64);
  return v;
}

// ---------------- Kernel 1: fused LayerNorm + KQV projection ------------
// Block: 256 threads (4 waves), PR=8 token rows.
//  A: stage x rows into LDS (coalesced float4)
//  B: LN in-place in LDS (each wave owns PR/4=2 rows)
//  C: each wave computes partial dots over its 128-wide f-chunk for all
//     8 rows x 3 projections (lane = d; weights coalesced, x via LDS bcast)
//  D: cross-wave LDS reduce + relu/sumnorm epilogue + store
// LDS 40 KB x 4 blocks/CU = 160 KB, 16 waves/CU.
__global__ __launch_bounds__(256, 4) void lnproj_k(
    const float* __restrict__ x,
    const float* __restrict__ gamma, const float* __restrict__ beta,
    const float* __restrict__ Wk, const float* __restrict__ Wq,
    const float* __restrict__ Wv,
    float* __restrict__ Ko, float* __restrict__ Qo, float* __restrict__ Vo) {
  __shared__ float lx[PR * FF];             // 16 KB
  __shared__ float part[4 * PR * 3 * DD];   // 24 KB
  const int tid = threadIdx.x;
  const int wv = tid >> 6, lane = tid & 63;
  const size_t row0 = (size_t)blockIdx.x * PR;

  { // A: stage
    const float4* xg = (const float4*)(x + row0 * FF);
    float4* lx4 = (float4*)lx;
    #pragma unroll
    for (int i = 0; i < (PR * FF / 4) / 256; ++i)
      lx4[tid + 256 * i] = xg[tid + 256 * i];
  }
  __syncthreads();

  { // B: layernorm in LDS
    float g[FF / 64], bt[FF / 64];
    #pragma unroll
    for (int k = 0; k < FF / 64; ++k) {
      g[k]  = gamma[lane + 64 * k];
      bt[k] = beta[lane + 64 * k];
    }
    #pragma unroll
    for (int rr = 0; rr < PR / 4; ++rr) {
      int r = wv * (PR / 4) + rr;
      float v[FF / 64];
      float s = 0.f, ss = 0.f;
      #pragma unroll
      for (int k = 0; k < FF / 64; ++k) {
        v[k] = lx[r * FF + lane + 64 * k];
        s += v[k]; ss += v[k] * v[k];
      }
      s = wave_sum64(s); ss = wave_sum64(ss);
      float m = s * (1.f / FF);
      float var = ss * (1.f / FF) - m * m;
      float rs = rsqrtf(var + 1e-5f);
      #pragma unroll
      for (int k = 0; k < FF / 64; ++k)
        lx[r * FF + lane + 64 * k] = (v[k] - m) * rs * g[k] + bt[k];
    }
  }
  __syncthreads();

  // C: partial dot-products over this wave's f-chunk
  float acc[PR][3];
  #pragma unroll
  for (int r = 0; r < PR; ++r)
    #pragma unroll
    for (int p = 0; p < 3; ++p) acc[r][p] = 0.f;

  const int fbase = wv * (FF / 4);
  #pragma unroll 2
  for (int f0 = fbase; f0 < fbase + FF / 4; f0 += 4) {
    float wk0 = Wk[(f0 + 0) * DD + lane], wk1 = Wk[(f0 + 1) * DD + lane];
    float wk2 = Wk[(f0 + 2) * DD + lane], wk3 = Wk[(f0 + 3) * DD + lane];
    float wq0 = Wq[(f0 + 0) * DD + lane], wq1 = Wq[(f0 + 1) * DD + lane];
    float wq2 = Wq[(f0 + 2) * DD + lane], wq3 = Wq[(f0 + 3) * DD + lane];
    float wv0 = Wv[(f0 + 0) * DD + lane], wv1 = Wv[(f0 + 1) * DD + lane];
    float wv2 = Wv[(f0 + 2) * DD + lane], wv3 = Wv[(f0 + 3) * DD + lane];
    #pragma unroll
    for (int r = 0; r < PR; ++r) {
      float4 xv = *(const float4*)&lx[r * FF + f0];
      acc[r][0] += (xv.x * wk0 + xv.y * wk1) + (xv.z * wk2 + xv.w * wk3);
      acc[r][1] += (xv.x * wq0 + xv.y * wq1) + (xv.z * wq2 + xv.w * wq3);
      acc[r][2] += (xv.x * wv0 + xv.y * wv1) + (xv.z * wv2 + xv.w * wv3);
    }
  }

  // D: cross-wave reduce + epilogue
  #pragma unroll
  for (int r = 0; r < PR; ++r)
    #pragma unroll
    for (int p = 0; p < 3; ++p)
      part[((wv * PR + r) * 3 + p) * DD + lane] = acc[r][p];
  __syncthreads();

  #pragma unroll
  for (int i = 0; i < (PR * 3) / 4; ++i) {   // 6 (row,proj) pairs per wave
    int pid = wv * ((PR * 3) / 4) + i;
    int r = pid / 3, p = pid - r * 3;
    float val = part[((0 * PR + r) * 3 + p) * DD + lane]
              + part[((1 * PR + r) * 3 + p) * DD + lane]
              + part[((2 * PR + r) * 3 + p) * DD + lane]
              + part[((3 * PR + r) * 3 + p) * DD + lane];
    float* outp = (p == 0) ? Ko : (p == 1) ? Qo : Vo;
    if (p < 2) {
      val = fmaxf(val, 0.f);
      float sm = wave_sum64(val);
      val = val / (1e-5f + sm);
    }
    outp[(row0 + r) * DD + lane] = val;
  }
}

// ---------------- Kernel 2: per-chunk outer-product sums ----------------
__global__ __launch_bounds__(256) void chunksum_k(const float* __restrict__ Kx,
                                                  const float* __restrict__ Vx,
                                                  float* __restrict__ S) {
  int bc = blockIdx.x, tid = threadIdx.x;
  __shared__ float lk[LCH * DD], lv[LCH * DD];
  for (int e = tid; e < LCH * DD; e += 256) {
    lk[e] = Kx[(size_t)bc * LCH * DD + e];
    lv[e] = Vx[(size_t)bc * LCH * DD + e];
  }
  __syncthreads();
  int j = tid & 63, i0 = (tid >> 6) << 4;
  float acc[16];
  #pragma unroll
  for (int ii = 0; ii < 16; ++ii) acc[ii] = 0.f;
  for (int t = 0; t < LCH; ++t) {
    float kj = lk[t * DD + j];
    #pragma unroll
    for (int ii = 0; ii < 16; ++ii) acc[ii] += lv[t * DD + i0 + ii] * kj;
  }
  float* Sp = S + (size_t)bc * (DD * DD);
  #pragma unroll
  for (int ii = 0; ii < 16; ++ii) Sp[(i0 + ii) * DD + j] = acc[ii];
}

// ---------------- Kernel 3: exclusive prefix over chunks ----------------
__global__ __launch_bounds__(256) void prefix_k(const float* __restrict__ S,
                                                const float* __restrict__ st0,
                                                float* __restrict__ P) {
  int b = blockIdx.x >> 4;
  int e = ((blockIdx.x & 15) << 8) + threadIdx.x;
  float run = st0[(size_t)b * (DD * DD) + e];
  const float* Sb = S + ((size_t)b * CCH) * (DD * DD) + e;
  float* Pb = P + ((size_t)b * CCH) * (DD * DD) + e;
  for (int c = 0; c < CCH; ++c) {
    Pb[(size_t)c * (DD * DD)] = run;
    run += Sb[(size_t)c * (DD * DD)];
  }
}

// ---------------- Kernel 4: in-chunk scan + y (fp32 outputs!) ----------
__global__ __launch_bounds__(64) void scan_k(const float* __restrict__ Kx,
                     const float* __restrict__ Qx, const float* __restrict__ Vx,
                     const float* __restrict__ P,
                     float* __restrict__ y, float* __restrict__ sout) {
  int bc = blockIdx.x, j = threadIdx.x;
  float S[DD];
  const float* Pp = P + (size_t)bc * (DD * DD);
  #pragma unroll
  for (int i = 0; i < DD; ++i) S[i] = Pp[i * DD + j];
  const float* Kb = Kx + (size_t)bc * LCH * DD;
  const float* Vb = Vx + (size_t)bc * LCH * DD;
  const float* Qb = Qx + (size_t)bc * LCH * DD;
  float kreg[LCH];
  #pragma unroll
  for (int t = 0; t < LCH; ++t) kreg[t] = Kb[t * DD + j];
  float* so = sout + (size_t)bc * LCH * (DD * DD) + j;
  float* yo = y + (size_t)bc * LCH * DD + j;
  for (int t = 0; t < LCH; ++t) {
    const float* Vt = Vb + t * DD;   // wave-uniform -> scalar loads
    const float* Qt = Qb + t * DD;
    float kj = kreg[t];
    float y0 = 0.f, y1 = 0.f, y2 = 0.f, y3 = 0.f;
    float* sot = so + (size_t)t * (DD * DD);
    #pragma unroll
    for (int i = 0; i < DD; i += 4) {
      S[i]     += Vt[i]     * kj; sot[(i)     * DD] = S[i];     y0 += S[i]     * Qt[i];
      S[i + 1] += Vt[i + 1] * kj; sot[(i + 1) * DD] = S[i + 1]; y1 += S[i + 1] * Qt[i + 1];
      S[i + 2] += Vt[i + 2] * kj; sot[(i + 2) * DD] = S[i + 2]; y2 += S[i + 2] * Qt[i + 2];
      S[i + 3] += Vt[i + 3] * kj; sot[(i + 3) * DD] = S[i + 3]; y3 += S[i + 3] * Qt[i + 3];
    }
    yo[t * DD] = (y0 + y1) + (y2 + y3);
  }
}

extern "C" void kernel_launch(void* const* d_in, const int* in_sizes, int n_in,
                              void* d_out, int out_size, void* d_ws, size_t ws_size,
                              hipStream_t stream) {
  const float* x     = (const float*)d_in[0];
  const float* st0   = (const float*)d_in[1];
  const float* Wk    = (const float*)d_in[2];
  const float* Wq    = (const float*)d_in[3];
  const float* Wv    = (const float*)d_in[4];
  const float* gamma = (const float*)d_in[5];
  const float* beta  = (const float*)d_in[6];

  float* out  = (float*)d_out;                    // fp32 — reference dtype!
  float* yout = out;                              // y [B,T,D] first
  float* sseq = out + (size_t)BB * TT * DD;       // state_seq [B,T,D,D]

  float* ws = (float*)d_ws;
  float* Ko = ws;
  float* Qo = Ko + (size_t)BB * TT * DD;
  float* Vo = Qo + (size_t)BB * TT * DD;
  float* S  = Vo + (size_t)BB * TT * DD;
  float* P  = S  + (size_t)BB * CCH * DD * DD;

  lnproj_k  <<<BB * TT / PR, 256, 0, stream>>>(x, gamma, beta, Wk, Wq, Wv, Ko, Qo, Vo);
  chunksum_k<<<BB * CCH, 256, 0, stream>>>(Ko, Vo, S);
  prefix_k  <<<BB * 16, 256, 0, stream>>>(S, st0, P);
  scan_k    <<<BB * CCH, 64, 0, stream>>>(Ko, Qo, Vo, P, yout, sseq);
}

// Round 2
// 210.313 us; speedup vs baseline: 1.1966x; 1.0076x over previous
//
#include <hip/hip_runtime.h>

#define BB 8
#define TT 1024
#define FF 512
#define DD 64
#define LCH 16
#define CCH (TT / LCH)
#define PR 8   // token rows per lnproj block

__device__ __forceinline__ float wave_sum64(float v) {
  #pragma unroll
  for (int m = 32; m >= 1; m >>= 1) v += __shfl_xor(v, m, 64);
  return v;
}

// ---------------- Kernel 1: fused LayerNorm + KQV projection ------------
__global__ __launch_bounds__(256, 4) void lnproj_k(
    const float* __restrict__ x,
    const float* __restrict__ gamma, const float* __restrict__ beta,
    const float* __restrict__ Wk, const float* __restrict__ Wq,
    const float* __restrict__ Wv,
    float* __restrict__ Ko, float* __restrict__ Qo, float* __restrict__ Vo) {
  __shared__ float lx[PR * FF];             // 16 KB
  __shared__ float part[4 * PR * 3 * DD];   // 24 KB
  const int tid = threadIdx.x;
  const int wv = tid >> 6, lane = tid & 63;
  const size_t row0 = (size_t)blockIdx.x * PR;

  { // A: stage
    const float4* xg = (const float4*)(x + row0 * FF);
    float4* lx4 = (float4*)lx;
    #pragma unroll
    for (int i = 0; i < (PR * FF / 4) / 256; ++i)
      lx4[tid + 256 * i] = xg[tid + 256 * i];
  }
  __syncthreads();

  { // B: layernorm in LDS
    float g[FF / 64], bt[FF / 64];
    #pragma unroll
    for (int k = 0; k < FF / 64; ++k) {
      g[k]  = gamma[lane + 64 * k];
      bt[k] = beta[lane + 64 * k];
    }
    #pragma unroll
    for (int rr = 0; rr < PR / 4; ++rr) {
      int r = wv * (PR / 4) + rr;
      float v[FF / 64];
      float s = 0.f, ss = 0.f;
      #pragma unroll
      for (int k = 0; k < FF / 64; ++k) {
        v[k] = lx[r * FF + lane + 64 * k];
        s += v[k]; ss += v[k] * v[k];
      }
      s = wave_sum64(s); ss = wave_sum64(ss);
      float m = s * (1.f / FF);
      float var = ss * (1.f / FF) - m * m;
      float rs = rsqrtf(var + 1e-5f);
      #pragma unroll
      for (int k = 0; k < FF / 64; ++k)
        lx[r * FF + lane + 64 * k] = (v[k] - m) * rs * g[k] + bt[k];
    }
  }
  __syncthreads();

  // C: partial dot-products over this wave's f-chunk
  float acc[PR][3];
  #pragma unroll
  for (int r = 0; r < PR; ++r)
    #pragma unroll
    for (int p = 0; p < 3; ++p) acc[r][p] = 0.f;

  const int fbase = wv * (FF / 4);
  #pragma unroll 2
  for (int f0 = fbase; f0 < fbase + FF / 4; f0 += 4) {
    float wk0 = Wk[(f0 + 0) * DD + lane], wk1 = Wk[(f0 + 1) * DD + lane];
    float wk2 = Wk[(f0 + 2) * DD + lane], wk3 = Wk[(f0 + 3) * DD + lane];
    float wq0 = Wq[(f0 + 0) * DD + lane], wq1 = Wq[(f0 + 1) * DD + lane];
    float wq2 = Wq[(f0 + 2) * DD + lane], wq3 = Wq[(f0 + 3) * DD + lane];
    float wv0 = Wv[(f0 + 0) * DD + lane], wv1 = Wv[(f0 + 1) * DD + lane];
    float wv2 = Wv[(f0 + 2) * DD + lane], wv3 = Wv[(f0 + 3) * DD + lane];
    #pragma unroll
    for (int r = 0; r < PR; ++r) {
      float4 xv = *(const float4*)&lx[r * FF + f0];
      acc[r][0] += (xv.x * wk0 + xv.y * wk1) + (xv.z * wk2 + xv.w * wk3);
      acc[r][1] += (xv.x * wq0 + xv.y * wq1) + (xv.z * wq2 + xv.w * wq3);
      acc[r][2] += (xv.x * wv0 + xv.y * wv1) + (xv.z * wv2 + xv.w * wv3);
    }
  }

  // D: cross-wave reduce + epilogue
  #pragma unroll
  for (int r = 0; r < PR; ++r)
    #pragma unroll
    for (int p = 0; p < 3; ++p)
      part[((wv * PR + r) * 3 + p) * DD + lane] = acc[r][p];
  __syncthreads();

  #pragma unroll
  for (int i = 0; i < (PR * 3) / 4; ++i) {   // 6 (row,proj) pairs per wave
    int pid = wv * ((PR * 3) / 4) + i;
    int r = pid / 3, p = pid - r * 3;
    float val = part[((0 * PR + r) * 3 + p) * DD + lane]
              + part[((1 * PR + r) * 3 + p) * DD + lane]
              + part[((2 * PR + r) * 3 + p) * DD + lane]
              + part[((3 * PR + r) * 3 + p) * DD + lane];
    float* outp = (p == 0) ? Ko : (p == 1) ? Qo : Vo;
    if (p < 2) {
      val = fmaxf(val, 0.f);
      float sm = wave_sum64(val);
      val = val / (1e-5f + sm);
    }
    outp[(row0 + r) * DD + lane] = val;
  }
}

// ---------------- Kernel 2: per-chunk outer-product sums ----------------
__global__ __launch_bounds__(256) void chunksum_k(const float* __restrict__ Kx,
                                                  const float* __restrict__ Vx,
                                                  float* __restrict__ S) {
  int bc = blockIdx.x, tid = threadIdx.x;
  __shared__ float lk[LCH * DD], lv[LCH * DD];
  for (int e = tid; e < LCH * DD; e += 256) {
    lk[e] = Kx[(size_t)bc * LCH * DD + e];
    lv[e] = Vx[(size_t)bc * LCH * DD + e];
  }
  __syncthreads();
  int j = tid & 63, i0 = (tid >> 6) << 4;
  float acc[16];
  #pragma unroll
  for (int ii = 0; ii < 16; ++ii) acc[ii] = 0.f;
  for (int t = 0; t < LCH; ++t) {
    float kj = lk[t * DD + j];
    #pragma unroll
    for (int ii = 0; ii < 16; ++ii) acc[ii] += lv[t * DD + i0 + ii] * kj;
  }
  float* Sp = S + (size_t)bc * (DD * DD);
  #pragma unroll
  for (int ii = 0; ii < 16; ++ii) Sp[(i0 + ii) * DD + j] = acc[ii];
}

// ---------------- Kernel 3: exclusive prefix over chunks ----------------
__global__ __launch_bounds__(256) void prefix_k(const float* __restrict__ S,
                                                const float* __restrict__ st0,
                                                float* __restrict__ P) {
  int b = blockIdx.x >> 4;
  int e = ((blockIdx.x & 15) << 8) + threadIdx.x;
  float run = st0[(size_t)b * (DD * DD) + e];
  const float* Sb = S + ((size_t)b * CCH) * (DD * DD) + e;
  float* Pb = P + ((size_t)b * CCH) * (DD * DD) + e;
  for (int c = 0; c < CCH; ++c) {
    Pb[(size_t)c * (DD * DD)] = run;
    run += Sb[(size_t)c * (DD * DD)];
  }
}

// ---------------- Kernel 4: in-chunk scan + y, 4-wave i-split ----------
// Block: 256 threads (4 waves). Wave wv owns state rows i0=wv*16..+15.
// Per t: each wave updates its 16 rows, stores them, accumulates a
// partial y into LDS; one sync at the end, then cross-wave y reduce.
__global__ __launch_bounds__(256) void scan_k(const float* __restrict__ Kx,
                     const float* __restrict__ Qx, const float* __restrict__ Vx,
                     const float* __restrict__ P,
                     float* __restrict__ y, float* __restrict__ sout) {
  int bc = blockIdx.x, tid = threadIdx.x;
  int wv = tid >> 6, j = tid & 63;
  int i0 = wv * 16;
  __shared__ float yp[4][LCH][DD];   // 16 KB
  float S[16];
  const float* Pp = P + (size_t)bc * (DD * DD);
  #pragma unroll
  for (int ii = 0; ii < 16; ++ii) S[ii] = Pp[(i0 + ii) * DD + j];
  const float* Kb = Kx + (size_t)bc * LCH * DD;
  const float* Vb = Vx + (size_t)bc * LCH * DD;
  const float* Qb = Qx + (size_t)bc * LCH * DD;
  float kreg[LCH];
  #pragma unroll
  for (int t = 0; t < LCH; ++t) kreg[t] = Kb[t * DD + j];
  float* so = sout + (size_t)bc * LCH * (DD * DD) + (size_t)i0 * DD + j;
  for (int t = 0; t < LCH; ++t) {
    const float* Vt = Vb + t * DD + i0;   // wave-uniform -> scalar loads
    const float* Qt = Qb + t * DD + i0;
    float kj = kreg[t];
    float y0 = 0.f, y1 = 0.f, y2 = 0.f, y3 = 0.f;
    float* sot = so + (size_t)t * (DD * DD);
    #pragma unroll
    for (int ii = 0; ii < 16; ii += 4) {
      S[ii]     += Vt[ii]     * kj; sot[(ii)     * DD] = S[ii];     y0 += S[ii]     * Qt[ii];
      S[ii + 1] += Vt[ii + 1] * kj; sot[(ii + 1) * DD] = S[ii + 1]; y1 += S[ii + 1] * Qt[ii + 1];
      S[ii + 2] += Vt[ii + 2] * kj; sot[(ii + 2) * DD] = S[ii + 2]; y2 += S[ii + 2] * Qt[ii + 2];
      S[ii + 3] += Vt[ii + 3] * kj; sot[(ii + 3) * DD] = S[ii + 3]; y3 += S[ii + 3] * Qt[ii + 3];
    }
    yp[wv][t][j] = (y0 + y1) + (y2 + y3);
  }
  __syncthreads();
  float* yo = y + (size_t)bc * LCH * DD;
  #pragma unroll
  for (int tt = 0; tt < LCH / 4; ++tt) {
    int t = wv * (LCH / 4) + tt;
    yo[t * DD + j] = (yp[0][t][j] + yp[1][t][j]) + (yp[2][t][j] + yp[3][t][j]);
  }
}

extern "C" void kernel_launch(void* const* d_in, const int* in_sizes, int n_in,
                              void* d_out, int out_size, void* d_ws, size_t ws_size,
                              hipStream_t stream) {
  const float* x     = (const float*)d_in[0];
  const float* st0   = (const float*)d_in[1];
  const float* Wk    = (const float*)d_in[2];
  const float* Wq    = (const float*)d_in[3];
  const float* Wv    = (const float*)d_in[4];
  const float* gamma = (const float*)d_in[5];
  const float* beta  = (const float*)d_in[6];

  float* out  = (float*)d_out;                    // fp32 — reference dtype!
  float* yout = out;                              // y [B,T,D] first
  float* sseq = out + (size_t)BB * TT * DD;       // state_seq [B,T,D,D]

  float* ws = (float*)d_ws;
  float* Ko = ws;
  float* Qo = Ko + (size_t)BB * TT * DD;
  float* Vo = Qo + (size_t)BB * TT * DD;
  float* S  = Vo + (size_t)BB * TT * DD;
  float* P  = S  + (size_t)BB * CCH * DD * DD;

  lnproj_k  <<<BB * TT / PR, 256, 0, stream>>>(x, gamma, beta, Wk, Wq, Wv, Ko, Qo, Vo);
  chunksum_k<<<BB * CCH, 256, 0, stream>>>(Ko, Vo, S);
  prefix_k  <<<BB * 16, 256, 0, stream>>>(S, st0, P);
  scan_k    <<<BB * CCH, 256, 0, stream>>>(Ko, Qo, Vo, P, yout, sseq);
}